// Round 1
// baseline (7470.647 us; speedup 1.0000x reference)
//
#include <hip/hip_runtime.h>

#define BB 8
#define NN 8192
#define NP 2048
#define KNbr 16
#define FIN 64
#define NPOS (BB*NP*KNbr)   // 262144 positions

// exact-order sum of squares: (x*x + y*y) + z*z, no FMA contraction
__device__ __forceinline__ float sq3(float x, float y, float z) {
  return __fadd_rn(__fadd_rn(__fmul_rn(x,x), __fmul_rn(y,y)), __fmul_rn(z,z));
}

// ---------------- build (x,y,z,|p|^2) AOS ----------------
__global__ __launch_bounds__(256) void k_xyzw(const float* __restrict__ xyz,
                                              float4* __restrict__ xyzw) {
  int g = blockIdx.x*256 + threadIdx.x;     // < BB*NN
  int b = g >> 13, n = g & (NN-1);
  const float* p = xyz + (size_t)b*3*NN;
  float x = p[n], y = p[NN+n], z = p[2*NN+n];
  xyzw[g] = make_float4(x, y, z, sq3(x,y,z));
}

// ---------------- FPS: one block per batch ----------------
__global__ __launch_bounds__(1024) void k_fps(const float4* __restrict__ xyzw,
                                              float4* __restrict__ qw,
                                              int* __restrict__ fpsidx,
                                              float* __restrict__ newxyz) {
  __shared__ float wmax[16];
  __shared__ int winner;
  __shared__ float cen[3];
  int b = blockIdx.x, tid = threadIdx.x;
  const float4* base = xyzw + (size_t)b*NN;
  float px[8], py[8], pz[8], dist[8];
  #pragma unroll
  for (int j=0;j<8;++j) {
    float4 p = base[j*1024+tid];
    px[j]=p.x; py[j]=p.y; pz[j]=p.z; dist[j]=1e10f;
  }
  float* outx = newxyz + (size_t)b*3*NP;
  if (tid==0) {
    float4 p0 = base[0];
    cen[0]=p0.x; cen[1]=p0.y; cen[2]=p0.z;
    fpsidx[b*NP] = 0;
    qw[b*NP] = p0;
    outx[0]=p0.x; outx[NP]=p0.y; outx[2*NP]=p0.z;
  }
  __syncthreads();
  for (int t=1;t<NP;++t) {
    float cx=cen[0], cy=cen[1], cz=cen[2];
    if (tid==0) winner = 0x7fffffff;
    float lmax = -1.0f;
    #pragma unroll
    for (int j=0;j<8;++j) {
      float dx=__fsub_rn(px[j],cx), dy=__fsub_rn(py[j],cy), dz=__fsub_rn(pz[j],cz);
      float d = sq3(dx,dy,dz);
      dist[j] = fminf(dist[j], d);
      lmax = fmaxf(lmax, dist[j]);
    }
    #pragma unroll
    for (int off=32; off>=1; off>>=1) lmax = fmaxf(lmax, __shfl_xor(lmax, off, 64));
    if ((tid&63)==0) wmax[tid>>6] = lmax;
    __syncthreads();
    float gmax = wmax[0];
    #pragma unroll
    for (int w=1;w<16;++w) gmax = fmaxf(gmax, wmax[w]);
    int cand = 0x7fffffff;
    #pragma unroll
    for (int j=7;j>=0;--j) if (dist[j]==gmax) cand = j*1024+tid;  // smallest own index
    if (cand != 0x7fffffff) atomicMin(&winner, cand);             // smallest global index
    __syncthreads();
    int w = winner;
    if ((w & 1023) == tid) {
      int jj = w >> 10;
      float wx=px[0], wy=py[0], wz=pz[0];
      #pragma unroll
      for (int j=1;j<8;++j) if (jj==j){wx=px[j];wy=py[j];wz=pz[j];}
      cen[0]=wx; cen[1]=wy; cen[2]=wz;
      fpsidx[b*NP+t] = w;
      qw[b*NP+t] = make_float4(wx,wy,wz,sq3(wx,wy,wz));
      outx[t]=wx; outx[NP+t]=wy; outx[2*NP+t]=wz;
    }
    __syncthreads();
  }
}

// ---------------- pre1: W1[:,3:67] @ points + b1, per original point ----------------
__global__ __launch_bounds__(256) void k_pre1(const float* __restrict__ pts,
                                              const float* __restrict__ W1,
                                              const float* __restrict__ b1,
                                              float* __restrict__ pre) {
  int g = blockIdx.x*256 + threadIdx.x;   // b*NN+n
  int b = g >> 13, n = g & (NN-1);
  const float* P = pts + (size_t)b*FIN*NN + n;
  float p[64];
  #pragma unroll
  for (int i=0;i<64;++i) p[i] = P[(size_t)i*NN];
  float4* out = (float4*)(pre + (size_t)g*64);
  for (int og=0; og<16; ++og) {
    float acc[4];
    #pragma unroll
    for (int oo=0;oo<4;++oo) {
      int o = og*4+oo;
      float s = b1[o];
      #pragma unroll
      for (int i=0;i<64;++i) s = fmaf(W1[o*67+3+i], p[i], s);
      acc[oo] = s;
    }
    out[og] = make_float4(acc[0],acc[1],acc[2],acc[3]);
  }
}

// ---------------- KNN: sorted top-16 per (query, half) ----------------
__device__ __forceinline__ void ins16(float (&d)[16], int (&ii)[16], float v, int vi) {
  bool done = false;
  #pragma unroll
  for (int j=15;j>=1;--j) {
    bool c = v < d[j-1];
    float nd = c ? d[j-1] : (done ? d[j] : v);
    int   ni = c ? ii[j-1] : (done ? ii[j] : vi);
    d[j]=nd; ii[j]=ni;
    done = done || !c;
  }
  if (!done) { d[0]=v; ii[0]=vi; }
}

__global__ __launch_bounds__(256) void k_knn(const float4* __restrict__ xyzw,
                                             const float4* __restrict__ qw,
                                             float* __restrict__ partd,
                                             int* __restrict__ parti) {
  __shared__ float4 tile[1024];
  int g = blockIdx.x*256 + threadIdx.x;   // b*4096 + s*2048 + q
  int b = g >> 12, s = (g >> 11) & 1, q = g & (NP-1);
  float4 Q = qw[b*NP + q];
  float d[16]; int id[16];
  #pragma unroll
  for (int j=0;j<16;++j){ d[j]=3.0e38f; id[j]=0x7fffffff; }
  const float4* base = xyzw + (size_t)b*NN + s*4096;
  for (int tI=0; tI<4; ++tI) {
    for (int l = threadIdx.x; l < 1024; l += 256) tile[l] = base[tI*1024 + l];
    __syncthreads();
    int idxbase = s*4096 + tI*1024;
    for (int c = 0; c < 1024; ++c) {
      float4 P = tile[c];
      float dot = __fadd_rn(__fadd_rn(__fmul_rn(P.x,Q.x), __fmul_rn(P.y,Q.y)), __fmul_rn(P.z,Q.z));
      float dd  = __fsub_rn(__fadd_rn(Q.w, P.w), __fmul_rn(2.0f, dot));
      if (dd < d[15]) ins16(d, id, dd, idxbase + c);
    }
    __syncthreads();
  }
  int p = ((b*NP + q)*2 + s)*16;
  #pragma unroll
  for (int j=0;j<16;++j){ partd[p+j]=d[j]; parti[p+j]=id[j]; }
}

__global__ __launch_bounds__(256) void k_merge(const float* __restrict__ pd,
                                               const int* __restrict__ pi,
                                               int* __restrict__ knn) {
  int g = blockIdx.x*256 + threadIdx.x;   // b*NP+q
  int p0 = g*32, p1 = p0+16;
  int* out = knn + g*16;
  int a=0, c=0;
  for (int r=0;r<16;++r) {
    float da = pd[p0+a], db = pd[p1+c];
    bool ta = (da <= db);        // tie -> lower split -> lower global index
    out[r] = ta ? pi[p0+a] : pi[p1+c];
    a += ta ? 1 : 0; c += ta ? 0 : 1;
  }
}

// ---------------- y1 = W1[:,0:3]@(gxyz - qxyz) + pre1[n] ----------------
__global__ __launch_bounds__(256) void k_y1(const float4* __restrict__ xyzw,
                                            const float4* __restrict__ qw,
                                            const int* __restrict__ knn,
                                            const float* __restrict__ pre,
                                            const float* __restrict__ W1,
                                            float* __restrict__ y) {
  int pos = blockIdx.x*256 + threadIdx.x;   // < NPOS
  int bq = pos >> 4;
  int b  = pos >> 15;
  int n  = knn[pos];
  float4 Q = qw[bq];
  float4 P = xyzw[(b<<13) + n];
  float dx = __fsub_rn(P.x,Q.x), dy = __fsub_rn(P.y,Q.y), dz = __fsub_rn(P.z,Q.z);
  const float4* pr = (const float4*)(pre + ((size_t)(b<<13)+n)*64);
  float4* out = (float4*)(y + (size_t)pos*64);
  for (int og=0; og<16; ++og) {
    float4 acc = pr[og];
    float a[4] = {acc.x, acc.y, acc.z, acc.w};
    #pragma unroll
    for (int oo=0;oo<4;++oo) {
      int o = og*4+oo;
      a[oo] = fmaf(W1[o*67+0], dx, fmaf(W1[o*67+1], dy, fmaf(W1[o*67+2], dz, a[oo])));
    }
    out[og] = make_float4(a[0],a[1],a[2],a[3]);
  }
}

// ---------------- per-channel sum / sumsq ----------------
__global__ __launch_bounds__(256) void k_stats(const float* __restrict__ y,
                                               float* __restrict__ st) {
  __shared__ float s1[256], s2[256];
  int tid = threadIdx.x; int c = tid & 63, r = tid >> 6;
  size_t base = (size_t)blockIdx.x * 1024;
  float sum = 0.f, ss = 0.f;
  for (int i=0;i<256;++i) {
    float v = y[(base + (size_t)i*4 + r)*64 + c];
    sum += v; ss = fmaf(v, v, ss);
  }
  s1[tid]=sum; s2[tid]=ss;
  __syncthreads();
  if (tid < 64) {
    float t1 = s1[tid]+s1[tid+64]+s1[tid+128]+s1[tid+192];
    float t2 = s2[tid]+s2[tid+64]+s2[tid+128]+s2[tid+192];
    atomicAdd(&st[tid], t1);
    atomicAdd(&st[64+tid], t2);
  }
}

__global__ void k_bnp(const float* __restrict__ st, const float* __restrict__ g,
                      const float* __restrict__ be, float* __restrict__ bnp) {
  int c = threadIdx.x;     // 64
  float mean = st[c] * (1.0f/NPOS);
  float var  = st[64+c] * (1.0f/NPOS) - mean*mean;
  float istd = 1.0f / sqrtf(var + 1e-5f);
  float s = g[c]*istd;
  bnp[c] = s;
  bnp[64+c] = be[c] - mean*s;
}

// ---------------- conv2 in-place: y <- W2 @ relu(bn1(y)) + b2 ----------------
__global__ __launch_bounds__(256) void k_conv2(float* __restrict__ y,
                                               const float* __restrict__ W2,
                                               const float* __restrict__ b2,
                                               const float* __restrict__ bnp) {
  size_t pos = (size_t)blockIdx.x*256 + threadIdx.x;
  float4* yp = (float4*)(y + pos*64);
  float x[64];
  #pragma unroll
  for (int i4=0;i4<16;++i4) {
    float4 v = yp[i4];
    int i = i4*4;
    x[i]   = fmaxf(0.f, fmaf(v.x, bnp[i],   bnp[64+i]));
    x[i+1] = fmaxf(0.f, fmaf(v.y, bnp[i+1], bnp[64+i+1]));
    x[i+2] = fmaxf(0.f, fmaf(v.z, bnp[i+2], bnp[64+i+2]));
    x[i+3] = fmaxf(0.f, fmaf(v.w, bnp[i+3], bnp[64+i+3]));
  }
  for (int og=0; og<16; ++og) {
    float acc[4];
    #pragma unroll
    for (int oo=0;oo<4;++oo) {
      int o = og*4+oo;
      float s = b2[o];
      #pragma unroll
      for (int i=0;i<64;++i) s = fmaf(W2[o*64+i], x[i], s);
      acc[oo] = s;
    }
    yp[og] = make_float4(acc[0],acc[1],acc[2],acc[3]);
  }
}

// ---------------- conv3 + max over K ----------------
__global__ __launch_bounds__(256) void k_c3(const float* __restrict__ y,
                                            const float* __restrict__ W3,
                                            const float* __restrict__ b3,
                                            const float* __restrict__ bnp2,
                                            float* __restrict__ feat) {
  int g = blockIdx.x*256 + threadIdx.x;    // 65536: og outer, then b, then q
  int q = g & (NP-1), b = (g >> 11) & 7, og = g >> 14;   // og in [0,4)
  size_t posbase = ((size_t)(b*NP + q))*16;
  float m[32];
  #pragma unroll
  for (int o=0;o<32;++o) m[o] = -3.0e38f;
  for (int k=0;k<16;++k) {
    const float4* xp = (const float4*)(y + (posbase+k)*64);
    float x[64];
    #pragma unroll
    for (int i4=0;i4<16;++i4) {
      float4 v = xp[i4];
      int i = i4*4;
      x[i]   = fmaxf(0.f, fmaf(v.x, bnp2[i],   bnp2[64+i]));
      x[i+1] = fmaxf(0.f, fmaf(v.y, bnp2[i+1], bnp2[64+i+1]));
      x[i+2] = fmaxf(0.f, fmaf(v.z, bnp2[i+2], bnp2[64+i+2]));
      x[i+3] = fmaxf(0.f, fmaf(v.w, bnp2[i+3], bnp2[64+i+3]));
    }
    #pragma unroll
    for (int o=0;o<32;++o) {
      int O = og*32+o;
      float s = b3[O];
      #pragma unroll
      for (int i=0;i<64;++i) s = fmaf(W3[O*64+i], x[i], s);
      m[o] = fmaxf(m[o], s);
    }
  }
  float* out = feat + ((size_t)b*128 + og*32)*NP + q;
  #pragma unroll
  for (int o=0;o<32;++o) out[(size_t)o*NP] = m[o];
}

extern "C" void kernel_launch(void* const* d_in, const int* in_sizes, int n_in,
                              void* d_out, int out_size, void* d_ws, size_t ws_size,
                              hipStream_t stream) {
  const float* xyz = (const float*)d_in[0];
  const float* pts = (const float*)d_in[1];
  const float* W1  = (const float*)d_in[2];
  const float* b1  = (const float*)d_in[3];
  const float* g1  = (const float*)d_in[4];
  const float* be1 = (const float*)d_in[5];
  const float* W2  = (const float*)d_in[6];
  const float* b2  = (const float*)d_in[7];
  const float* g2  = (const float*)d_in[8];
  const float* be2 = (const float*)d_in[9];
  const float* W3  = (const float*)d_in[10];
  const float* b3  = (const float*)d_in[11];
  float* out = (float*)d_out;
  float* ws  = (float*)d_ws;

  // workspace layout (float offsets)
  float4* xyzw  = (float4*)ws;                    //  65536 float4
  float4* qw    = (float4*)(ws + 262144);         //  16384 float4
  int*    fpsid = (int*)(ws + 327680);            //  16384
  int*    knnid = (int*)(ws + 344064);            //  262144
  float*  partd = ws + 606208;                    //  524288
  int*    parti = (int*)(ws + 1130496);           //  524288
  float*  pre   = ws + 1654784;                   //  4194304
  float*  ybuf  = ws + 5849088;                   //  16777216
  float*  stats = ws + 22626304;                  //  256 (layer1: [0..127], layer2: [128..255])
  float*  bnp   = ws + 22626560;                  //  256 (layer1: [0..127], layer2: [128..255])

  hipMemsetAsync(stats, 0, 256*sizeof(float), stream);

  k_xyzw <<<256, 256, 0, stream>>>(xyz, xyzw);
  k_pre1 <<<256, 256, 0, stream>>>(pts, W1, b1, pre);
  k_fps  <<<8, 1024, 0, stream>>>(xyzw, qw, fpsid, out);
  k_knn  <<<128, 256, 0, stream>>>(xyzw, qw, partd, parti);
  k_merge<<<64, 256, 0, stream>>>(partd, parti, knnid);
  k_y1   <<<1024, 256, 0, stream>>>(xyzw, qw, knnid, pre, W1, ybuf);
  k_stats<<<256, 256, 0, stream>>>(ybuf, stats);
  k_bnp  <<<1, 64, 0, stream>>>(stats, g1, be1, bnp);
  k_conv2<<<1024, 256, 0, stream>>>(ybuf, W2, b2, bnp);
  k_stats<<<256, 256, 0, stream>>>(ybuf, stats + 128);
  k_bnp  <<<1, 64, 0, stream>>>(stats + 128, g2, be2, bnp + 128);
  k_c3   <<<256, 256, 0, stream>>>(ybuf, W3, b3, bnp + 128, out + 49152);
}

// Round 2
// 4762.754 us; speedup vs baseline: 1.5686x; 1.5686x over previous
//
#include <hip/hip_runtime.h>

#define BB 8
#define NN 8192
#define NP 2048
#define KNbr 16
#define FIN 64
#define NPOS (BB*NP*KNbr)   // 262144 positions

// exact-order sum of squares: (x*x + y*y) + z*z, no FMA contraction
__device__ __forceinline__ float sq3(float x, float y, float z) {
  return __fadd_rn(__fadd_rn(__fmul_rn(x,x), __fmul_rn(y,y)), __fmul_rn(z,z));
}

// ---------------- build (x,y,z,|p|^2) AOS ----------------
__global__ __launch_bounds__(256) void k_xyzw(const float* __restrict__ xyz,
                                              float4* __restrict__ xyzw) {
  int g = blockIdx.x*256 + threadIdx.x;     // < BB*NN
  int b = g >> 13, n = g & (NN-1);
  const float* p = xyz + (size_t)b*3*NN;
  float x = p[n], y = p[NN+n], z = p[2*NN+n];
  xyzw[g] = make_float4(x, y, z, sq3(x,y,z));
}

// ---------------- FPS v2: 256 threads, 1 barrier/iter, u64-key reduce ----------------
__global__ __launch_bounds__(256) void k_fps(const float4* __restrict__ xyzw,
                                             float4* __restrict__ qw,
                                             int* __restrict__ fpsidx,
                                             float* __restrict__ newxyz) {
  __shared__ unsigned long long skey[2][4];
  __shared__ float sx[2][4], sy[2][4], sz[2][4];
  int b = blockIdx.x, tid = threadIdx.x;
  const float4* base = xyzw + (size_t)b*NN;
  float px[32], py[32], pz[32], dist[32];
  #pragma unroll
  for (int j=0;j<32;++j) {
    float4 p = base[j*256+tid];
    px[j]=p.x; py[j]=p.y; pz[j]=p.z; dist[j]=1e10f;
  }
  float* outx = newxyz + (size_t)b*3*NP;
  float4 p0 = base[0];
  float cx=p0.x, cy=p0.y, cz=p0.z;
  if (tid==0) {
    fpsidx[b*NP] = 0;
    qw[b*NP] = make_float4(p0.x,p0.y,p0.z,sq3(p0.x,p0.y,p0.z));
    outx[0]=p0.x; outx[NP]=p0.y; outx[2*NP]=p0.z;
  }
  int w = tid>>6;
  for (int t=1;t<NP;++t) {
    float lmax = -1.0f; int lj = 0; float bx=0.f,by=0.f,bz=0.f;
    #pragma unroll
    for (int j=0;j<32;++j) {
      float dx=__fsub_rn(px[j],cx), dy=__fsub_rn(py[j],cy), dz=__fsub_rn(pz[j],cz);
      float d = sq3(dx,dy,dz);
      float nd = fminf(dist[j], d);
      dist[j] = nd;
      if (nd > lmax) { lmax = nd; lj = j; bx = px[j]; by = py[j]; bz = pz[j]; }
    }
    unsigned int lidx = (unsigned)(lj*256 + tid);
    unsigned long long key =
      ((unsigned long long)__float_as_uint(lmax) << 32) | (unsigned long long)(0xFFFFFFFFu - lidx);
    unsigned long long rk = key;
    #pragma unroll
    for (int off=32; off>=1; off>>=1) {
      unsigned long long o = __shfl_xor(rk, off, 64);
      rk = (o > rk) ? o : rk;
    }
    int buf = t & 1;
    if (rk == key) {   // unique winner lane of each wave
      skey[buf][w] = rk; sx[buf][w]=bx; sy[buf][w]=by; sz[buf][w]=bz;
    }
    __syncthreads();
    unsigned long long k0=skey[buf][0], k1=skey[buf][1], k2=skey[buf][2], k3=skey[buf][3];
    int w01 = (k1>k0)?1:0; unsigned long long m01 = (k1>k0)?k1:k0;
    int w23 = (k3>k2)?3:2; unsigned long long m23 = (k3>k2)?k3:k2;
    int wi = (m23>m01)?w23:w01; unsigned long long mk = (m23>m01)?m23:m01;
    cx = sx[buf][wi]; cy = sy[buf][wi]; cz = sz[buf][wi];
    if (tid==0) {
      unsigned widx = 0xFFFFFFFFu - (unsigned)mk;
      fpsidx[b*NP+t] = (int)widx;
      qw[b*NP+t] = make_float4(cx,cy,cz,sq3(cx,cy,cz));
      outx[t]=cx; outx[NP+t]=cy; outx[2*NP+t]=cz;
    }
  }
}

// ---------------- pre1: W1[:,3:67] @ points + b1, per original point ----------------
__global__ __launch_bounds__(256) void k_pre1(const float* __restrict__ pts,
                                              const float* __restrict__ W1,
                                              const float* __restrict__ b1,
                                              float* __restrict__ pre) {
  int g = blockIdx.x*256 + threadIdx.x;   // b*NN+n
  int b = g >> 13, n = g & (NN-1);
  const float* P = pts + (size_t)b*FIN*NN + n;
  float p[64];
  #pragma unroll
  for (int i=0;i<64;++i) p[i] = P[(size_t)i*NN];
  float4* out = (float4*)(pre + (size_t)g*64);
  for (int og=0; og<16; ++og) {
    float acc[4];
    #pragma unroll
    for (int oo=0;oo<4;++oo) {
      int o = og*4+oo;
      float s = b1[o];
      #pragma unroll
      for (int i=0;i<64;++i) s = fmaf(W1[o*67+3+i], p[i], s);
      acc[oo] = s;
    }
    out[og] = make_float4(acc[0],acc[1],acc[2],acc[3]);
  }
}

// ---------------- KNN: sorted top-16 per (query, half) ----------------
__device__ __forceinline__ void ins16(float (&d)[16], int (&ii)[16], float v, int vi) {
  bool done = false;
  #pragma unroll
  for (int j=15;j>=1;--j) {
    bool c = v < d[j-1];
    float nd = c ? d[j-1] : (done ? d[j] : v);
    int   ni = c ? ii[j-1] : (done ? ii[j] : vi);
    d[j]=nd; ii[j]=ni;
    done = done || !c;
  }
  if (!done) { d[0]=v; ii[0]=vi; }
}

__global__ __launch_bounds__(256) void k_knn(const float4* __restrict__ xyzw,
                                             const float4* __restrict__ qw,
                                             float* __restrict__ partd,
                                             int* __restrict__ parti) {
  __shared__ float4 tile[1024];
  int g = blockIdx.x*256 + threadIdx.x;   // b*4096 + s*2048 + q
  int b = g >> 12, s = (g >> 11) & 1, q = g & (NP-1);
  float4 Q = qw[b*NP + q];
  float d[16]; int id[16];
  #pragma unroll
  for (int j=0;j<16;++j){ d[j]=3.0e38f; id[j]=0x7fffffff; }
  const float4* base = xyzw + (size_t)b*NN + s*4096;
  for (int tI=0; tI<4; ++tI) {
    for (int l = threadIdx.x; l < 1024; l += 256) tile[l] = base[tI*1024 + l];
    __syncthreads();
    int idxbase = s*4096 + tI*1024;
    for (int c = 0; c < 1024; ++c) {
      float4 P = tile[c];
      float dot = __fadd_rn(__fadd_rn(__fmul_rn(P.x,Q.x), __fmul_rn(P.y,Q.y)), __fmul_rn(P.z,Q.z));
      float dd  = __fsub_rn(__fadd_rn(Q.w, P.w), __fmul_rn(2.0f, dot));
      if (dd < d[15]) ins16(d, id, dd, idxbase + c);
    }
    __syncthreads();
  }
  int p = ((b*NP + q)*2 + s)*16;
  #pragma unroll
  for (int j=0;j<16;++j){ partd[p+j]=d[j]; parti[p+j]=id[j]; }
}

__global__ __launch_bounds__(256) void k_merge(const float* __restrict__ pd,
                                               const int* __restrict__ pi,
                                               int* __restrict__ knn) {
  int g = blockIdx.x*256 + threadIdx.x;   // b*NP+q
  int p0 = g*32, p1 = p0+16;
  int* out = knn + g*16;
  int a=0, c=0;
  for (int r=0;r<16;++r) {
    float da = pd[p0+a], db = pd[p1+c];
    bool ta = (da <= db);        // tie -> lower split -> lower global index
    out[r] = ta ? pi[p0+a] : pi[p1+c];
    a += ta ? 1 : 0; c += ta ? 0 : 1;
  }
}

// ---------------- y1 = W1[:,0:3]@(gxyz - qxyz) + pre1[n] ----------------
__global__ __launch_bounds__(256) void k_y1(const float4* __restrict__ xyzw,
                                            const float4* __restrict__ qw,
                                            const int* __restrict__ knn,
                                            const float* __restrict__ pre,
                                            const float* __restrict__ W1,
                                            float* __restrict__ y) {
  int pos = blockIdx.x*256 + threadIdx.x;   // < NPOS
  int bq = pos >> 4;
  int b  = pos >> 15;
  int n  = knn[pos];
  float4 Q = qw[bq];
  float4 P = xyzw[(b<<13) + n];
  float dx = __fsub_rn(P.x,Q.x), dy = __fsub_rn(P.y,Q.y), dz = __fsub_rn(P.z,Q.z);
  const float4* pr = (const float4*)(pre + ((size_t)(b<<13)+n)*64);
  float4* out = (float4*)(y + (size_t)pos*64);
  for (int og=0; og<16; ++og) {
    float4 acc = pr[og];
    float a[4] = {acc.x, acc.y, acc.z, acc.w};
    #pragma unroll
    for (int oo=0;oo<4;++oo) {
      int o = og*4+oo;
      a[oo] = fmaf(W1[o*67+0], dx, fmaf(W1[o*67+1], dy, fmaf(W1[o*67+2], dz, a[oo])));
    }
    out[og] = make_float4(a[0],a[1],a[2],a[3]);
  }
}

// ---------------- per-channel sum / sumsq ----------------
__global__ __launch_bounds__(256) void k_stats(const float* __restrict__ y,
                                               float* __restrict__ st) {
  __shared__ float s1[256], s2[256];
  int tid = threadIdx.x; int c = tid & 63, r = tid >> 6;
  size_t base = (size_t)blockIdx.x * 1024;
  float sum = 0.f, ss = 0.f;
  for (int i=0;i<256;++i) {
    float v = y[(base + (size_t)i*4 + r)*64 + c];
    sum += v; ss = fmaf(v, v, ss);
  }
  s1[tid]=sum; s2[tid]=ss;
  __syncthreads();
  if (tid < 64) {
    float t1 = s1[tid]+s1[tid+64]+s1[tid+128]+s1[tid+192];
    float t2 = s2[tid]+s2[tid+64]+s2[tid+128]+s2[tid+192];
    atomicAdd(&st[tid], t1);
    atomicAdd(&st[64+tid], t2);
  }
}

__global__ void k_bnp(const float* __restrict__ st, const float* __restrict__ g,
                      const float* __restrict__ be, float* __restrict__ bnp) {
  int c = threadIdx.x;     // 64
  float mean = st[c] * (1.0f/NPOS);
  float var  = st[64+c] * (1.0f/NPOS) - mean*mean;
  float istd = 1.0f / sqrtf(var + 1e-5f);
  float s = g[c]*istd;
  bnp[c] = s;
  bnp[64+c] = be[c] - mean*s;
}

// ---------------- act: in-place x = relu(s*x + t) ----------------
__global__ __launch_bounds__(256) void k_act(float* __restrict__ y,
                                             const float* __restrict__ bnp) {
  size_t g = (size_t)blockIdx.x*256 + threadIdx.x;   // 1,048,576 threads
  float4* Y = (float4*)y;
  #pragma unroll
  for (int r=0;r<4;++r) {
    size_t f4 = g + (size_t)r*1048576;               // 4,194,304 float4 total
    int c0 = (int)((f4*4) & 63);
    float4 s4 = *(const float4*)(bnp + c0);
    float4 t4 = *(const float4*)(bnp + 64 + c0);
    float4 v = Y[f4];
    v.x = fmaxf(0.f, fmaf(v.x, s4.x, t4.x));
    v.y = fmaxf(0.f, fmaf(v.y, s4.y, t4.y));
    v.z = fmaxf(0.f, fmaf(v.z, s4.z, t4.z));
    v.w = fmaxf(0.f, fmaf(v.w, s4.w, t4.w));
    Y[f4] = v;
  }
}

// ---------------- dot of 64 with 4 partial accumulators ----------------
__device__ __forceinline__ float dot64(const float4* x, const float* W, float init) {
  float a0 = init, a1 = 0.f, a2 = 0.f, a3 = 0.f;
  #pragma unroll
  for (int j=0;j<16;++j) {
    float4 v = x[j];
    a0 = fmaf(v.x, W[4*j],   a0);
    a1 = fmaf(v.y, W[4*j+1], a1);
    a2 = fmaf(v.z, W[4*j+2], a2);
    a3 = fmaf(v.w, W[4*j+3], a3);
  }
  return (a0+a1)+(a2+a3);
}

// ---------------- conv2: W in VGPRs (lane=out ch), in-place ----------------
__global__ __launch_bounds__(256) void k_conv2v(float* __restrict__ y,
                                                const float* __restrict__ W2,
                                                const float* __restrict__ b2) {
  int wid = blockIdx.x*4 + (threadIdx.x>>6);   // 0..2047
  int lane = threadIdx.x & 63;
  float W[64];
  #pragma unroll
  for (int j=0;j<16;++j) {
    float4 t = *(const float4*)(W2 + (size_t)lane*64 + j*4);
    W[4*j]=t.x; W[4*j+1]=t.y; W[4*j+2]=t.z; W[4*j+3]=t.w;
  }
  float bb = b2[lane];
  size_t p0 = (size_t)wid*128;
  const float4* src = (const float4*)(y + p0*64);
  float4 xa[16], xb[16];
  #pragma unroll
  for (int j=0;j<16;++j) xa[j] = src[j];
  for (int p=0;p<128;p+=2) {
    #pragma unroll
    for (int j=0;j<16;++j) xb[j] = src[(p+1)*16 + j];
    float acc = dot64(xa, W, bb);
    y[(p0+p)*64 + lane] = acc;
    if (p+2 < 128) {
      #pragma unroll
      for (int j=0;j<16;++j) xa[j] = src[(p+2)*16 + j];
    }
    float acc2 = dot64(xb, W, bb);
    y[(p0+p+1)*64 + lane] = acc2;
  }
}

// ---------------- conv3 + max over K: W in VGPRs, half-split ----------------
__global__ __launch_bounds__(256) void k_c3v(const float* __restrict__ y,
                                             const float* __restrict__ W3,
                                             const float* __restrict__ b3,
                                             float* __restrict__ feat) {
  int wid = blockIdx.x*4 + (threadIdx.x>>6);   // 0..2047
  int lane = threadIdx.x & 63;
  int h = wid & 1, chunk = wid >> 1;           // 1024 chunks x 16 queries
  float W[64];
  #pragma unroll
  for (int j=0;j<16;++j) {
    float4 t = *(const float4*)(W3 + ((size_t)(h*64+lane))*64 + j*4);
    W[4*j]=t.x; W[4*j+1]=t.y; W[4*j+2]=t.z; W[4*j+3]=t.w;
  }
  float bb = b3[h*64+lane];
  const float4* src = (const float4*)(y + (size_t)chunk*16*16*64);
  float4 xa[16], xb[16];
  #pragma unroll
  for (int j=0;j<16;++j) xa[j] = src[j];
  int pos = 0;
  for (int q=0;q<16;++q) {
    float m = -3.0e38f;
    #pragma unroll 1
    for (int k=0;k<16;k+=2) {
      #pragma unroll
      for (int j=0;j<16;++j) xb[j] = src[(pos+1)*16 + j];
      m = fmaxf(m, dot64(xa, W, bb));
      if (pos+2 < 256) {
        #pragma unroll
        for (int j=0;j<16;++j) xa[j] = src[(pos+2)*16 + j];
      }
      m = fmaxf(m, dot64(xb, W, bb));
      pos += 2;
    }
    int gq = chunk*16 + q;
    int b = gq >> 11, qq = gq & (NP-1);
    feat[((size_t)(b*128 + h*64 + lane))*NP + qq] = m;
  }
}

extern "C" void kernel_launch(void* const* d_in, const int* in_sizes, int n_in,
                              void* d_out, int out_size, void* d_ws, size_t ws_size,
                              hipStream_t stream) {
  const float* xyz = (const float*)d_in[0];
  const float* pts = (const float*)d_in[1];
  const float* W1  = (const float*)d_in[2];
  const float* b1  = (const float*)d_in[3];
  const float* g1  = (const float*)d_in[4];
  const float* be1 = (const float*)d_in[5];
  const float* W2  = (const float*)d_in[6];
  const float* b2  = (const float*)d_in[7];
  const float* g2  = (const float*)d_in[8];
  const float* be2 = (const float*)d_in[9];
  const float* W3  = (const float*)d_in[10];
  const float* b3  = (const float*)d_in[11];
  float* out = (float*)d_out;
  float* ws  = (float*)d_ws;

  // workspace layout (float offsets)
  float4* xyzw  = (float4*)ws;                    //  65536 float4
  float4* qw    = (float4*)(ws + 262144);         //  16384 float4
  int*    fpsid = (int*)(ws + 327680);            //  16384
  int*    knnid = (int*)(ws + 344064);            //  262144
  float*  partd = ws + 606208;                    //  524288
  int*    parti = (int*)(ws + 1130496);           //  524288
  float*  pre   = ws + 1654784;                   //  4194304
  float*  ybuf  = ws + 5849088;                   //  16777216
  float*  stats = ws + 22626304;                  //  256
  float*  bnp   = ws + 22626560;                  //  256

  hipMemsetAsync(stats, 0, 256*sizeof(float), stream);

  k_xyzw  <<<256, 256, 0, stream>>>(xyz, xyzw);
  k_pre1  <<<256, 256, 0, stream>>>(pts, W1, b1, pre);
  k_fps   <<<8, 256, 0, stream>>>(xyzw, qw, fpsid, out);
  k_knn   <<<128, 256, 0, stream>>>(xyzw, qw, partd, parti);
  k_merge <<<64, 256, 0, stream>>>(partd, parti, knnid);
  k_y1    <<<1024, 256, 0, stream>>>(xyzw, qw, knnid, pre, W1, ybuf);
  k_stats <<<256, 256, 0, stream>>>(ybuf, stats);
  k_bnp   <<<1, 64, 0, stream>>>(stats, g1, be1, bnp);
  k_act   <<<4096, 256, 0, stream>>>(ybuf, bnp);
  k_conv2v<<<512, 256, 0, stream>>>(ybuf, W2, b2);
  k_stats <<<256, 256, 0, stream>>>(ybuf, stats + 128);
  k_bnp   <<<1, 64, 0, stream>>>(stats + 128, g2, be2, bnp + 128);
  k_act   <<<4096, 256, 0, stream>>>(ybuf, bnp + 128);
  k_c3v   <<<512, 256, 0, stream>>>(ybuf, W3, b3, out + 49152);
}

// Round 3
// 4330.392 us; speedup vs baseline: 1.7252x; 1.0998x over previous
//
#include <hip/hip_runtime.h>

#define BB 8
#define NN 8192
#define NP 2048
#define KNbr 16
#define FIN 64
#define NPOS (BB*NP*KNbr)   // 262144 positions

// exact-order sum of squares: (x*x + y*y) + z*z, no FMA contraction
__device__ __forceinline__ float sq3(float x, float y, float z) {
  return __fadd_rn(__fadd_rn(__fmul_rn(x,x), __fmul_rn(y,y)), __fmul_rn(z,z));
}

// ---------------- build (x,y,z,|p|^2) AOS ----------------
__global__ __launch_bounds__(256) void k_xyzw(const float* __restrict__ xyz,
                                              float4* __restrict__ xyzw) {
  int g = blockIdx.x*256 + threadIdx.x;     // < BB*NN
  int b = g >> 13, n = g & (NN-1);
  const float* p = xyz + (size_t)b*3*NN;
  float x = p[n], y = p[NN+n], z = p[2*NN+n];
  xyzw[g] = make_float4(x, y, z, sq3(x,y,z));
}

// ---------------- FPS v3: 512 thr x 16 pts (no spill), 1 barrier/iter ----------------
__global__ __launch_bounds__(512,1) void k_fps(const float4* __restrict__ xyzw,
                                               float4* __restrict__ qw,
                                               int* __restrict__ fpsidx,
                                               float* __restrict__ newxyz) {
  __shared__ unsigned long long skey[2][8];
  __shared__ float4 scen[2][8];
  int b = blockIdx.x, tid = threadIdx.x;
  const float4* base = xyzw + (size_t)b*NN;
  float px[16], py[16], pz[16], dist[16];
  #pragma unroll
  for (int j=0;j<16;++j) {
    float4 p = base[j*512+tid];
    px[j]=p.x; py[j]=p.y; pz[j]=p.z; dist[j]=1e10f;
  }
  float* outx = newxyz + (size_t)b*3*NP;
  float4 p0 = base[0];
  float cx=p0.x, cy=p0.y, cz=p0.z;
  if (tid==0) {
    fpsidx[b*NP] = 0;
    qw[b*NP] = make_float4(p0.x,p0.y,p0.z,sq3(p0.x,p0.y,p0.z));
    outx[0]=p0.x; outx[NP]=p0.y; outx[2*NP]=p0.z;
  }
  int w = tid>>6;   // wave id 0..7
  for (int t=1;t<NP;++t) {
    float lmax = -1.0f; int lj = 0; float bx=0.f,by=0.f,bz=0.f;
    #pragma unroll
    for (int j=0;j<16;++j) {
      float dx=__fsub_rn(px[j],cx), dy=__fsub_rn(py[j],cy), dz=__fsub_rn(pz[j],cz);
      float d = sq3(dx,dy,dz);
      float nd = fminf(dist[j], d);
      dist[j] = nd;
      if (nd > lmax) { lmax = nd; lj = j; bx = px[j]; by = py[j]; bz = pz[j]; }
    }
    unsigned int lidx = (unsigned)(lj*512 + tid);
    unsigned long long key =
      ((unsigned long long)__float_as_uint(lmax) << 32) | (unsigned long long)(0xFFFFFFFFu - lidx);
    unsigned long long rk = key;
    #pragma unroll
    for (int off=32; off>=1; off>>=1) {
      unsigned long long o = __shfl_xor(rk, off, 64);
      rk = (o > rk) ? o : rk;
    }
    int buf = t & 1;
    if (rk == key) {   // unique winner lane of each wave
      skey[buf][w] = rk; scen[buf][w] = make_float4(bx,by,bz,0.f);
    }
    __syncthreads();
    unsigned long long mk = skey[buf][0]; int wi = 0;
    #pragma unroll
    for (int i=1;i<8;++i) {
      unsigned long long k = skey[buf][i];
      if (k > mk) { mk = k; wi = i; }
    }
    float4 c = scen[buf][wi];
    cx = c.x; cy = c.y; cz = c.z;
    if (tid==0) {
      unsigned widx = 0xFFFFFFFFu - (unsigned)mk;
      fpsidx[b*NP+t] = (int)widx;
      qw[b*NP+t] = make_float4(cx,cy,cz,sq3(cx,cy,cz));
      outx[t]=cx; outx[NP+t]=cy; outx[2*NP+t]=cz;
    }
  }
}

// ---------------- pre1: W1[:,3:67] @ points + b1, per original point ----------------
__global__ __launch_bounds__(256) void k_pre1(const float* __restrict__ pts,
                                              const float* __restrict__ W1,
                                              const float* __restrict__ b1,
                                              float* __restrict__ pre) {
  int g = blockIdx.x*256 + threadIdx.x;   // b*NN+n
  int b = g >> 13, n = g & (NN-1);
  const float* P = pts + (size_t)b*FIN*NN + n;
  float p[64];
  #pragma unroll
  for (int i=0;i<64;++i) p[i] = P[(size_t)i*NN];
  float4* out = (float4*)(pre + (size_t)g*64);
  for (int og=0; og<16; ++og) {
    float acc[4];
    #pragma unroll
    for (int oo=0;oo<4;++oo) {
      int o = og*4+oo;
      float s = b1[o];
      #pragma unroll
      for (int i=0;i<64;++i) s = fmaf(W1[o*67+3+i], p[i], s);
      acc[oo] = s;
    }
    out[og] = make_float4(acc[0],acc[1],acc[2],acc[3]);
  }
}

// ---------------- KNN: sorted top-16 per (query, half) ----------------
__device__ __forceinline__ void ins16(float (&d)[16], int (&ii)[16], float v, int vi) {
  bool done = false;
  #pragma unroll
  for (int j=15;j>=1;--j) {
    bool c = v < d[j-1];
    float nd = c ? d[j-1] : (done ? d[j] : v);
    int   ni = c ? ii[j-1] : (done ? ii[j] : vi);
    d[j]=nd; ii[j]=ni;
    done = done || !c;
  }
  if (!done) { d[0]=v; ii[0]=vi; }
}

__global__ __launch_bounds__(256) void k_knn(const float4* __restrict__ xyzw,
                                             const float4* __restrict__ qw,
                                             float* __restrict__ partd,
                                             int* __restrict__ parti) {
  __shared__ float4 tile[1024];
  int g = blockIdx.x*256 + threadIdx.x;   // b*4096 + s*2048 + q
  int b = g >> 12, s = (g >> 11) & 1, q = g & (NP-1);
  float4 Q = qw[b*NP + q];
  float d[16]; int id[16];
  #pragma unroll
  for (int j=0;j<16;++j){ d[j]=3.0e38f; id[j]=0x7fffffff; }
  const float4* base = xyzw + (size_t)b*NN + s*4096;
  for (int tI=0; tI<4; ++tI) {
    for (int l = threadIdx.x; l < 1024; l += 256) tile[l] = base[tI*1024 + l];
    __syncthreads();
    int idxbase = s*4096 + tI*1024;
    for (int c = 0; c < 1024; ++c) {
      float4 P = tile[c];
      float dot = __fadd_rn(__fadd_rn(__fmul_rn(P.x,Q.x), __fmul_rn(P.y,Q.y)), __fmul_rn(P.z,Q.z));
      float dd  = __fsub_rn(__fadd_rn(Q.w, P.w), __fmul_rn(2.0f, dot));
      if (dd < d[15]) ins16(d, id, dd, idxbase + c);
    }
    __syncthreads();
  }
  int p = ((b*NP + q)*2 + s)*16;
  #pragma unroll
  for (int j=0;j<16;++j){ partd[p+j]=d[j]; parti[p+j]=id[j]; }
}

__global__ __launch_bounds__(256) void k_merge(const float* __restrict__ pd,
                                               const int* __restrict__ pi,
                                               int* __restrict__ knn) {
  int g = blockIdx.x*256 + threadIdx.x;   // b*NP+q
  int p0 = g*32, p1 = p0+16;
  int* out = knn + g*16;
  int a=0, c=0;
  for (int r=0;r<16;++r) {
    float da = pd[p0+a], db = pd[p1+c];
    bool ta = (da <= db);        // tie -> lower split -> lower global index
    out[r] = ta ? pi[p0+a] : pi[p1+c];
    a += ta ? 1 : 0; c += ta ? 0 : 1;
  }
}

// ---------------- y1 = W1[:,0:3]@(gxyz - qxyz) + pre1[n] ----------------
__global__ __launch_bounds__(256) void k_y1(const float4* __restrict__ xyzw,
                                            const float4* __restrict__ qw,
                                            const int* __restrict__ knn,
                                            const float* __restrict__ pre,
                                            const float* __restrict__ W1,
                                            float* __restrict__ y) {
  int pos = blockIdx.x*256 + threadIdx.x;   // < NPOS
  int bq = pos >> 4;
  int b  = pos >> 15;
  int n  = knn[pos];
  float4 Q = qw[bq];
  float4 P = xyzw[(b<<13) + n];
  float dx = __fsub_rn(P.x,Q.x), dy = __fsub_rn(P.y,Q.y), dz = __fsub_rn(P.z,Q.z);
  const float4* pr = (const float4*)(pre + ((size_t)(b<<13)+n)*64);
  float4* out = (float4*)(y + (size_t)pos*64);
  for (int og=0; og<16; ++og) {
    float4 acc = pr[og];
    float a[4] = {acc.x, acc.y, acc.z, acc.w};
    #pragma unroll
    for (int oo=0;oo<4;++oo) {
      int o = og*4+oo;
      a[oo] = fmaf(W1[o*67+0], dx, fmaf(W1[o*67+1], dy, fmaf(W1[o*67+2], dz, a[oo])));
    }
    out[og] = make_float4(a[0],a[1],a[2],a[3]);
  }
}

// ---------------- per-channel sum / sumsq ----------------
__global__ __launch_bounds__(256) void k_stats(const float* __restrict__ y,
                                               float* __restrict__ st) {
  __shared__ float s1[256], s2[256];
  int tid = threadIdx.x; int c = tid & 63, r = tid >> 6;
  size_t base = (size_t)blockIdx.x * 1024;
  float sum = 0.f, ss = 0.f;
  for (int i=0;i<256;++i) {
    float v = y[(base + (size_t)i*4 + r)*64 + c];
    sum += v; ss = fmaf(v, v, ss);
  }
  s1[tid]=sum; s2[tid]=ss;
  __syncthreads();
  if (tid < 64) {
    float t1 = s1[tid]+s1[tid+64]+s1[tid+128]+s1[tid+192];
    float t2 = s2[tid]+s2[tid+64]+s2[tid+128]+s2[tid+192];
    atomicAdd(&st[tid], t1);
    atomicAdd(&st[64+tid], t2);
  }
}

__global__ void k_bnp(const float* __restrict__ st, const float* __restrict__ g,
                      const float* __restrict__ be, float* __restrict__ bnp) {
  int c = threadIdx.x;     // 64
  float mean = st[c] * (1.0f/NPOS);
  float var  = st[64+c] * (1.0f/NPOS) - mean*mean;
  float istd = 1.0f / sqrtf(var + 1e-5f);
  float s = g[c]*istd;
  bnp[c] = s;
  bnp[64+c] = be[c] - mean*s;
}

// ---------------- act: in-place x = relu(s*x + t) ----------------
__global__ __launch_bounds__(256) void k_act(float* __restrict__ y,
                                             const float* __restrict__ bnp) {
  size_t g = (size_t)blockIdx.x*256 + threadIdx.x;   // 1,048,576 threads
  float4* Y = (float4*)y;
  #pragma unroll
  for (int r=0;r<4;++r) {
    size_t f4 = g + (size_t)r*1048576;               // 4,194,304 float4 total
    int c0 = (int)((f4*4) & 63);
    float4 s4 = *(const float4*)(bnp + c0);
    float4 t4 = *(const float4*)(bnp + 64 + c0);
    float4 v = Y[f4];
    v.x = fmaxf(0.f, fmaf(v.x, s4.x, t4.x));
    v.y = fmaxf(0.f, fmaf(v.y, s4.y, t4.y));
    v.z = fmaxf(0.f, fmaf(v.z, s4.z, t4.z));
    v.w = fmaxf(0.f, fmaf(v.w, s4.w, t4.w));
    Y[f4] = v;
  }
}

// ---------------- dot of 64 with 4 partial accumulators ----------------
__device__ __forceinline__ float dot64(const float4* x, const float* W, float init) {
  float a0 = init, a1 = 0.f, a2 = 0.f, a3 = 0.f;
  #pragma unroll
  for (int j=0;j<16;++j) {
    float4 v = x[j];
    a0 = fmaf(v.x, W[4*j],   a0);
    a1 = fmaf(v.y, W[4*j+1], a1);
    a2 = fmaf(v.z, W[4*j+2], a2);
    a3 = fmaf(v.w, W[4*j+3], a3);
  }
  return (a0+a1)+(a2+a3);
}

// ---------------- conv2: W in VGPRs (lane=out ch), in-place ----------------
__global__ __launch_bounds__(256) void k_conv2v(float* __restrict__ y,
                                                const float* __restrict__ W2,
                                                const float* __restrict__ b2) {
  int wid = blockIdx.x*4 + (threadIdx.x>>6);   // 0..2047
  int lane = threadIdx.x & 63;
  float W[64];
  #pragma unroll
  for (int j=0;j<16;++j) {
    float4 t = *(const float4*)(W2 + (size_t)lane*64 + j*4);
    W[4*j]=t.x; W[4*j+1]=t.y; W[4*j+2]=t.z; W[4*j+3]=t.w;
  }
  float bb = b2[lane];
  size_t p0 = (size_t)wid*128;
  const float4* src = (const float4*)(y + p0*64);
  float4 xa[16], xb[16];
  #pragma unroll
  for (int j=0;j<16;++j) xa[j] = src[j];
  for (int p=0;p<128;p+=2) {
    #pragma unroll
    for (int j=0;j<16;++j) xb[j] = src[(p+1)*16 + j];
    float acc = dot64(xa, W, bb);
    y[(p0+p)*64 + lane] = acc;
    if (p+2 < 128) {
      #pragma unroll
      for (int j=0;j<16;++j) xa[j] = src[(p+2)*16 + j];
    }
    float acc2 = dot64(xb, W, bb);
    y[(p0+p+1)*64 + lane] = acc2;
  }
}

// ---------------- conv3 + max over K: W in VGPRs, half-split ----------------
__global__ __launch_bounds__(256) void k_c3v(const float* __restrict__ y,
                                             const float* __restrict__ W3,
                                             const float* __restrict__ b3,
                                             float* __restrict__ feat) {
  int wid = blockIdx.x*4 + (threadIdx.x>>6);   // 0..2047
  int lane = threadIdx.x & 63;
  int h = wid & 1, chunk = wid >> 1;           // 1024 chunks x 16 queries
  float W[64];
  #pragma unroll
  for (int j=0;j<16;++j) {
    float4 t = *(const float4*)(W3 + ((size_t)(h*64+lane))*64 + j*4);
    W[4*j]=t.x; W[4*j+1]=t.y; W[4*j+2]=t.z; W[4*j+3]=t.w;
  }
  float bb = b3[h*64+lane];
  const float4* src = (const float4*)(y + (size_t)chunk*16*16*64);
  float4 xa[16], xb[16];
  #pragma unroll
  for (int j=0;j<16;++j) xa[j] = src[j];
  int pos = 0;
  for (int q=0;q<16;++q) {
    float m = -3.0e38f;
    #pragma unroll 1
    for (int k=0;k<16;k+=2) {
      #pragma unroll
      for (int j=0;j<16;++j) xb[j] = src[(pos+1)*16 + j];
      m = fmaxf(m, dot64(xa, W, bb));
      if (pos+2 < 256) {
        #pragma unroll
        for (int j=0;j<16;++j) xa[j] = src[(pos+2)*16 + j];
      }
      m = fmaxf(m, dot64(xb, W, bb));
      pos += 2;
    }
    int gq = chunk*16 + q;
    int b = gq >> 11, qq = gq & (NP-1);
    feat[((size_t)(b*128 + h*64 + lane))*NP + qq] = m;
  }
}

extern "C" void kernel_launch(void* const* d_in, const int* in_sizes, int n_in,
                              void* d_out, int out_size, void* d_ws, size_t ws_size,
                              hipStream_t stream) {
  const float* xyz = (const float*)d_in[0];
  const float* pts = (const float*)d_in[1];
  const float* W1  = (const float*)d_in[2];
  const float* b1  = (const float*)d_in[3];
  const float* g1  = (const float*)d_in[4];
  const float* be1 = (const float*)d_in[5];
  const float* W2  = (const float*)d_in[6];
  const float* b2  = (const float*)d_in[7];
  const float* g2  = (const float*)d_in[8];
  const float* be2 = (const float*)d_in[9];
  const float* W3  = (const float*)d_in[10];
  const float* b3  = (const float*)d_in[11];
  float* out = (float*)d_out;
  float* ws  = (float*)d_ws;

  // workspace layout (float offsets)
  float4* xyzw  = (float4*)ws;                    //  65536 float4
  float4* qw    = (float4*)(ws + 262144);         //  16384 float4
  int*    fpsid = (int*)(ws + 327680);            //  16384
  int*    knnid = (int*)(ws + 344064);            //  262144
  float*  partd = ws + 606208;                    //  524288
  int*    parti = (int*)(ws + 1130496);           //  524288
  float*  pre   = ws + 1654784;                   //  4194304
  float*  ybuf  = ws + 5849088;                   //  16777216
  float*  stats = ws + 22626304;                  //  256
  float*  bnp   = ws + 22626560;                  //  256

  hipMemsetAsync(stats, 0, 256*sizeof(float), stream);

  k_xyzw  <<<256, 256, 0, stream>>>(xyz, xyzw);
  k_pre1  <<<256, 256, 0, stream>>>(pts, W1, b1, pre);
  k_fps   <<<8, 512, 0, stream>>>(xyzw, qw, fpsid, out);
  k_knn   <<<128, 256, 0, stream>>>(xyzw, qw, partd, parti);
  k_merge <<<64, 256, 0, stream>>>(partd, parti, knnid);
  k_y1    <<<1024, 256, 0, stream>>>(xyzw, qw, knnid, pre, W1, ybuf);
  k_stats <<<256, 256, 0, stream>>>(ybuf, stats);
  k_bnp   <<<1, 64, 0, stream>>>(stats, g1, be1, bnp);
  k_act   <<<4096, 256, 0, stream>>>(ybuf, bnp);
  k_conv2v<<<512, 256, 0, stream>>>(ybuf, W2, b2);
  k_stats <<<256, 256, 0, stream>>>(ybuf, stats + 128);
  k_bnp   <<<1, 64, 0, stream>>>(stats + 128, g2, be2, bnp + 128);
  k_act   <<<4096, 256, 0, stream>>>(ybuf, bnp + 128);
  k_c3v   <<<512, 256, 0, stream>>>(ybuf, W3, b3, out + 49152);
}

// Round 4
// 3316.449 us; speedup vs baseline: 2.2526x; 1.3057x over previous
//
#include <hip/hip_runtime.h>
#pragma clang fp contract(off)

#define BB 8
#define NN 8192
#define NP 2048
#define KNbr 16
#define FIN 64
#define NPOS (BB*NP*KNbr)   // 262144 positions

typedef float f32x2 __attribute__((ext_vector_type(2)));
typedef unsigned long long u64;

// exact-order sum of squares: (x*x + y*y) + z*z, no FMA contraction
__device__ __forceinline__ float sq3(float x, float y, float z) {
  return __fadd_rn(__fadd_rn(__fmul_rn(x,x), __fmul_rn(y,y)), __fmul_rn(z,z));
}

// ---------------- build (x,y,z,|p|^2) AOS ----------------
__global__ __launch_bounds__(256) void k_xyzw(const float* __restrict__ xyz,
                                              float4* __restrict__ xyzw) {
  int g = blockIdx.x*256 + threadIdx.x;     // < BB*NN
  int b = g >> 13, n = g & (NN-1);
  const float* p = xyz + (size_t)b*3*NN;
  float x = p[n], y = p[NN+n], z = p[2*NN+n];
  xyzw[g] = make_float4(x, y, z, sq3(x,y,z));
}

// ---------------- FPS v4: 256 thr x 32 pts packed f32x2, tree argmax ----------------
__global__ __launch_bounds__(256,1) void k_fps(const float4* __restrict__ xyzw,
                                               float4* __restrict__ qw,
                                               int* __restrict__ fpsidx,
                                               float* __restrict__ newxyz) {
  __shared__ u64 skey[2][4];
  int b = blockIdx.x, tid = threadIdx.x;
  const float4* base = xyzw + (size_t)b*NN;
  f32x2 px[16], py[16], pz[16], d2[16];
  #pragma unroll
  for (int j=0;j<16;++j) {
    float4 a = base[j*512 + 2*tid];
    float4 c = base[j*512 + 2*tid + 1];
    px[j] = f32x2{a.x, c.x};
    py[j] = f32x2{a.y, c.y};
    pz[j] = f32x2{a.z, c.z};
    d2[j] = f32x2{1e10f, 1e10f};
  }
  float* outx = newxyz + (size_t)b*3*NP;
  float4 p0 = base[0];
  float cx=p0.x, cy=p0.y, cz=p0.z;
  if (tid==0) {
    fpsidx[b*NP] = 0;
    qw[b*NP] = make_float4(p0.x,p0.y,p0.z,sq3(p0.x,p0.y,p0.z));
    outx[0]=p0.x; outx[NP]=p0.y; outx[2*NP]=p0.z;
  }
  int w = tid>>6;
  for (int t=1;t<NP;++t) {
    f32x2 cx2 = {cx,cx}, cy2 = {cy,cy}, cz2 = {cz,cz};
    #pragma unroll
    for (int j=0;j<16;++j) {
      f32x2 dx = px[j]-cx2, dy = py[j]-cy2, dz = pz[j]-cz2;
      f32x2 dd = (dx*dx + dy*dy) + dz*dz;     // contract(off): pk_mul/pk_add, per-op rounding
      d2[j].x = fminf(d2[j].x, dd.x);
      d2[j].y = fminf(d2[j].y, dd.y);
    }
    // argmax tree over 32 leaves; ties -> smaller k (strict-greater keeps left)
    float tv[16]; int tk[16];
    #pragma unroll
    for (int j=0;j<16;++j) {
      bool r = d2[j].y > d2[j].x;
      tv[j] = r ? d2[j].y : d2[j].x;
      tk[j] = r ? 2*j+1 : 2*j;
    }
    #pragma unroll
    for (int j=0;j<8;++j) { bool r = tv[j+8] > tv[j]; if (r){tv[j]=tv[j+8]; tk[j]=tk[j+8];} }
    #pragma unroll
    for (int j=0;j<4;++j) { bool r = tv[j+4] > tv[j]; if (r){tv[j]=tv[j+4]; tk[j]=tk[j+4];} }
    #pragma unroll
    for (int j=0;j<2;++j) { bool r = tv[j+2] > tv[j]; if (r){tv[j]=tv[j+2]; tk[j]=tk[j+2];} }
    bool rr = tv[1] > tv[0];
    float lmax = rr ? tv[1] : tv[0];
    int   k    = rr ? tk[1] : tk[0];
    unsigned gidx = (unsigned)((k>>1)*512 + 2*tid + (k&1));
    u64 key = ((u64)__float_as_uint(lmax) << 32) | (u64)(0xFFFFFFFFu - gidx);
    u64 rk = key;
    #pragma unroll
    for (int off=32; off>=1; off>>=1) {
      u64 o = __shfl_xor(rk, off, 64);
      rk = (o > rk) ? o : rk;
    }
    int buf = t & 1;
    if (rk == key) skey[buf][w] = rk;   // unique winner lane per wave
    __syncthreads();
    u64 mk = skey[buf][0];
    if (skey[buf][1] > mk) mk = skey[buf][1];
    if (skey[buf][2] > mk) mk = skey[buf][2];
    if (skey[buf][3] > mk) mk = skey[buf][3];
    unsigned widx = 0xFFFFFFFFu - (unsigned)(mk & 0xFFFFFFFFull);
    float4 cen = base[widx];            // wave-uniform broadcast load (L1/L2)
    cx = cen.x; cy = cen.y; cz = cen.z;
    if (tid==0) {
      fpsidx[b*NP+t] = (int)widx;
      qw[b*NP+t] = make_float4(cx,cy,cz,sq3(cx,cy,cz));
      outx[t]=cx; outx[NP+t]=cy; outx[2*NP+t]=cz;
    }
  }
}

// ---------------- pre1: W1[:,3:67] @ points + b1, per original point ----------------
__global__ __launch_bounds__(256) void k_pre1(const float* __restrict__ pts,
                                              const float* __restrict__ W1,
                                              const float* __restrict__ b1,
                                              float* __restrict__ pre) {
  int g = blockIdx.x*256 + threadIdx.x;   // b*NN+n
  int b = g >> 13, n = g & (NN-1);
  const float* P = pts + (size_t)b*FIN*NN + n;
  float p[64];
  #pragma unroll
  for (int i=0;i<64;++i) p[i] = P[(size_t)i*NN];
  float4* out = (float4*)(pre + (size_t)g*64);
  for (int og=0; og<16; ++og) {
    float acc[4];
    #pragma unroll
    for (int oo=0;oo<4;++oo) {
      int o = og*4+oo;
      float s = b1[o];
      #pragma unroll
      for (int i=0;i<64;++i) s = fmaf(W1[o*67+3+i], p[i], s);
      acc[oo] = s;
    }
    out[og] = make_float4(acc[0],acc[1],acc[2],acc[3]);
  }
}

// ---------------- KNN v2: one wave per query, lane-distributed sorted top-16 ----------------
__global__ __launch_bounds__(256) void k_knn(const float4* __restrict__ xyzw,
                                             const float4* __restrict__ qw,
                                             int* __restrict__ knnid) {
  int wave = threadIdx.x >> 6, lane = threadIdx.x & 63;
  int q = blockIdx.x*4 + wave;            // 0..16383
  int b = q >> 11;
  float4 Q = qw[q];
  const float4* base = xyzw + (size_t)b*NN;
  float ld = 3.0e38f; int li = 0x7fffffff;   // list entry (lanes 0..15), ascending (d,idx)
  float taud = 3.0e38f; int taui = 0x7fffffff;
  for (int c = 0; c < 128; ++c) {
    int idx = c*64 + lane;
    float4 P = base[idx];
    float dot = __fadd_rn(__fadd_rn(__fmul_rn(P.x,Q.x), __fmul_rn(P.y,Q.y)), __fmul_rn(P.z,Q.z));
    float dd  = __fsub_rn(__fadd_rn(Q.w, P.w), __fmul_rn(2.0f, dot));
    bool better = (dd < taud) || (dd == taud && idx < taui);
    u64 mask = __ballot(better);
    while (mask) {
      int src = __ffsll(mask) - 1;
      mask &= mask - 1;
      float bd = __shfl(dd, src, 64);
      int   bi = __shfl(idx, src, 64);
      bool before = (ld < bd) || (ld == bd && li < bi);
      float sd = __shfl_up(ld, 1, 64);
      int   si = __shfl_up(li, 1, 64);
      int   bp = __shfl_up((int)before, 1, 64);
      bool take_new = !before && (lane == 0 || bp);
      float nd = before ? ld : (take_new ? bd : sd);
      int   ni = before ? li : (take_new ? bi : si);
      if (lane < 16) { ld = nd; li = ni; }
      taud = __shfl(ld, 15, 64);
      taui = __shfl(li, 15, 64);
    }
  }
  if (lane < 16) knnid[q*16 + lane] = li;
}

// ---------------- y1 = W1[:,0:3]@(gxyz - qxyz) + pre1[n] ----------------
__global__ __launch_bounds__(256) void k_y1(const float4* __restrict__ xyzw,
                                            const float4* __restrict__ qw,
                                            const int* __restrict__ knn,
                                            const float* __restrict__ pre,
                                            const float* __restrict__ W1,
                                            float* __restrict__ y) {
  int pos = blockIdx.x*256 + threadIdx.x;   // < NPOS
  int bq = pos >> 4;
  int b  = pos >> 15;
  int n  = knn[pos];
  float4 Q = qw[bq];
  float4 P = xyzw[(b<<13) + n];
  float dx = __fsub_rn(P.x,Q.x), dy = __fsub_rn(P.y,Q.y), dz = __fsub_rn(P.z,Q.z);
  const float4* pr = (const float4*)(pre + ((size_t)(b<<13)+n)*64);
  float4* out = (float4*)(y + (size_t)pos*64);
  for (int og=0; og<16; ++og) {
    float4 acc = pr[og];
    float a[4] = {acc.x, acc.y, acc.z, acc.w};
    #pragma unroll
    for (int oo=0;oo<4;++oo) {
      int o = og*4+oo;
      a[oo] = fmaf(W1[o*67+0], dx, fmaf(W1[o*67+1], dy, fmaf(W1[o*67+2], dz, a[oo])));
    }
    out[og] = make_float4(a[0],a[1],a[2],a[3]);
  }
}

// ---------------- per-channel sum / sumsq (layer1) ----------------
__global__ __launch_bounds__(256) void k_stats(const float* __restrict__ y,
                                               float* __restrict__ st) {
  __shared__ float s1[256], s2[256];
  int tid = threadIdx.x; int c = tid & 63, r = tid >> 6;
  size_t base = (size_t)blockIdx.x * 1024;
  float sum = 0.f, ss = 0.f;
  for (int i=0;i<256;++i) {
    float v = y[(base + (size_t)i*4 + r)*64 + c];
    sum += v; ss = fmaf(v, v, ss);
  }
  s1[tid]=sum; s2[tid]=ss;
  __syncthreads();
  if (tid < 64) {
    float t1 = s1[tid]+s1[tid+64]+s1[tid+128]+s1[tid+192];
    float t2 = s2[tid]+s2[tid+64]+s2[tid+128]+s2[tid+192];
    atomicAdd(&st[tid], t1);
    atomicAdd(&st[64+tid], t2);
  }
}

__global__ void k_bnp(const float* __restrict__ st, const float* __restrict__ g,
                      const float* __restrict__ be, float* __restrict__ bnp) {
  int c = threadIdx.x;     // 64
  float mean = st[c] * (1.0f/NPOS);
  float var  = st[64+c] * (1.0f/NPOS) - mean*mean;
  float istd = 1.0f / sqrtf(var + 1e-5f);
  float s = g[c]*istd;
  bnp[c] = s;
  bnp[64+c] = be[c] - mean*s;
}

// ---------------- act: in-place x = relu(s*x + t) ----------------
__global__ __launch_bounds__(256) void k_act(float* __restrict__ y,
                                             const float* __restrict__ bnp) {
  size_t g = (size_t)blockIdx.x*256 + threadIdx.x;
  float4* Y = (float4*)y;
  #pragma unroll
  for (int r=0;r<4;++r) {
    size_t f4 = g + (size_t)r*1048576;               // 4,194,304 float4 total
    int c0 = (int)((f4*4) & 63);
    float4 s4 = *(const float4*)(bnp + c0);
    float4 t4 = *(const float4*)(bnp + 64 + c0);
    float4 v = Y[f4];
    v.x = fmaxf(0.f, fmaf(v.x, s4.x, t4.x));
    v.y = fmaxf(0.f, fmaf(v.y, s4.y, t4.y));
    v.z = fmaxf(0.f, fmaf(v.z, s4.z, t4.z));
    v.w = fmaxf(0.f, fmaf(v.w, s4.w, t4.w));
    Y[f4] = v;
  }
}

// ---------------- dot of 64 with 4 partial accumulators ----------------
__device__ __forceinline__ float dot64(const float4* x, const float* W, float init) {
  float a0 = init, a1 = 0.f, a2 = 0.f, a3 = 0.f;
  #pragma unroll
  for (int j=0;j<16;++j) {
    float4 v = x[j];
    a0 = fmaf(v.x, W[4*j],   a0);
    a1 = fmaf(v.y, W[4*j+1], a1);
    a2 = fmaf(v.z, W[4*j+2], a2);
    a3 = fmaf(v.w, W[4*j+3], a3);
  }
  return (a0+a1)+(a2+a3);
}

// ---------------- conv2: W in VGPRs (lane=out ch), in-place, fused stats2 ----------------
__global__ __launch_bounds__(256) void k_conv2v(float* __restrict__ y,
                                                const float* __restrict__ W2,
                                                const float* __restrict__ b2,
                                                float* __restrict__ st2) {
  __shared__ float r1[4][64], r2[4][64];
  int wave = threadIdx.x>>6;
  int wid = blockIdx.x*4 + wave;   // 0..2047
  int lane = threadIdx.x & 63;
  float W[64];
  #pragma unroll
  for (int j=0;j<16;++j) {
    float4 t = *(const float4*)(W2 + (size_t)lane*64 + j*4);
    W[4*j]=t.x; W[4*j+1]=t.y; W[4*j+2]=t.z; W[4*j+3]=t.w;
  }
  float bb = b2[lane];
  size_t p0 = (size_t)wid*128;
  const float4* src = (const float4*)(y + p0*64);
  float4 xa[16], xb[16];
  float sum = 0.f, ss = 0.f;
  #pragma unroll
  for (int j=0;j<16;++j) xa[j] = src[j];
  for (int p=0;p<128;p+=2) {
    #pragma unroll
    for (int j=0;j<16;++j) xb[j] = src[(p+1)*16 + j];
    float acc = dot64(xa, W, bb);
    y[(p0+p)*64 + lane] = acc;
    sum += acc; ss = fmaf(acc, acc, ss);
    if (p+2 < 128) {
      #pragma unroll
      for (int j=0;j<16;++j) xa[j] = src[(p+2)*16 + j];
    }
    float acc2 = dot64(xb, W, bb);
    y[(p0+p+1)*64 + lane] = acc2;
    sum += acc2; ss = fmaf(acc2, acc2, ss);
  }
  r1[wave][lane] = sum; r2[wave][lane] = ss;
  __syncthreads();
  if (threadIdx.x < 64) {
    int l = threadIdx.x;
    float t1 = r1[0][l]+r1[1][l]+r1[2][l]+r1[3][l];
    float t2 = r2[0][l]+r2[1][l]+r2[2][l]+r2[3][l];
    atomicAdd(&st2[l], t1);
    atomicAdd(&st2[64+l], t2);
  }
}

// ---------------- conv3 + max over K: W in VGPRs, half-split ----------------
__global__ __launch_bounds__(256) void k_c3v(const float* __restrict__ y,
                                             const float* __restrict__ W3,
                                             const float* __restrict__ b3,
                                             float* __restrict__ feat) {
  int wid = blockIdx.x*4 + (threadIdx.x>>6);   // 0..2047
  int lane = threadIdx.x & 63;
  int h = wid & 1, chunk = wid >> 1;           // 1024 chunks x 16 queries
  float W[64];
  #pragma unroll
  for (int j=0;j<16;++j) {
    float4 t = *(const float4*)(W3 + ((size_t)(h*64+lane))*64 + j*4);
    W[4*j]=t.x; W[4*j+1]=t.y; W[4*j+2]=t.z; W[4*j+3]=t.w;
  }
  float bb = b3[h*64+lane];
  const float4* src = (const float4*)(y + (size_t)chunk*16*16*64);
  float4 xa[16], xb[16];
  #pragma unroll
  for (int j=0;j<16;++j) xa[j] = src[j];
  int pos = 0;
  for (int q=0;q<16;++q) {
    float m = -3.0e38f;
    #pragma unroll 1
    for (int k=0;k<16;k+=2) {
      #pragma unroll
      for (int j=0;j<16;++j) xb[j] = src[(pos+1)*16 + j];
      m = fmaxf(m, dot64(xa, W, bb));
      if (pos+2 < 256) {
        #pragma unroll
        for (int j=0;j<16;++j) xa[j] = src[(pos+2)*16 + j];
      }
      m = fmaxf(m, dot64(xb, W, bb));
      pos += 2;
    }
    int gq = chunk*16 + q;
    int b = gq >> 11, qq = gq & (NP-1);
    feat[((size_t)(b*128 + h*64 + lane))*NP + qq] = m;
  }
}

extern "C" void kernel_launch(void* const* d_in, const int* in_sizes, int n_in,
                              void* d_out, int out_size, void* d_ws, size_t ws_size,
                              hipStream_t stream) {
  const float* xyz = (const float*)d_in[0];
  const float* pts = (const float*)d_in[1];
  const float* W1  = (const float*)d_in[2];
  const float* b1  = (const float*)d_in[3];
  const float* g1  = (const float*)d_in[4];
  const float* be1 = (const float*)d_in[5];
  const float* W2  = (const float*)d_in[6];
  const float* b2  = (const float*)d_in[7];
  const float* g2  = (const float*)d_in[8];
  const float* be2 = (const float*)d_in[9];
  const float* W3  = (const float*)d_in[10];
  const float* b3  = (const float*)d_in[11];
  float* out = (float*)d_out;
  float* ws  = (float*)d_ws;

  // workspace layout (float offsets)
  float4* xyzw  = (float4*)ws;                    //  65536 float4
  float4* qw    = (float4*)(ws + 262144);         //  16384 float4
  int*    fpsid = (int*)(ws + 327680);            //  16384
  int*    knnid = (int*)(ws + 344064);            //  262144
  float*  pre   = ws + 1654784;                   //  4194304
  float*  ybuf  = ws + 5849088;                   //  16777216
  float*  stats = ws + 22626304;                  //  256
  float*  bnp   = ws + 22626560;                  //  256

  hipMemsetAsync(stats, 0, 256*sizeof(float), stream);

  k_xyzw  <<<256, 256, 0, stream>>>(xyz, xyzw);
  k_pre1  <<<256, 256, 0, stream>>>(pts, W1, b1, pre);
  k_fps   <<<8, 256, 0, stream>>>(xyzw, qw, fpsid, out);
  k_knn   <<<4096, 256, 0, stream>>>(xyzw, qw, knnid);
  k_y1    <<<1024, 256, 0, stream>>>(xyzw, qw, knnid, pre, W1, ybuf);
  k_stats <<<256, 256, 0, stream>>>(ybuf, stats);
  k_bnp   <<<1, 64, 0, stream>>>(stats, g1, be1, bnp);
  k_act   <<<4096, 256, 0, stream>>>(ybuf, bnp);
  k_conv2v<<<512, 256, 0, stream>>>(ybuf, W2, b2, stats + 128);
  k_bnp   <<<1, 64, 0, stream>>>(stats + 128, g2, be2, bnp + 128);
  k_act   <<<4096, 256, 0, stream>>>(ybuf, bnp + 128);
  k_c3v   <<<512, 256, 0, stream>>>(ybuf, W3, b3, out + 49152);
}

// Round 5
// 2747.714 us; speedup vs baseline: 2.7189x; 1.2070x over previous
//
#include <hip/hip_runtime.h>
#pragma clang fp contract(off)

#define BB 8
#define NN 8192
#define NP 2048
#define KNbr 16
#define FIN 64
#define NPOS (BB*NP*KNbr)   // 262144 positions

typedef float f32x2 __attribute__((ext_vector_type(2)));
typedef unsigned long long u64;

// exact-order sum of squares: (x*x + y*y) + z*z, no FMA contraction
__device__ __forceinline__ float sq3(float x, float y, float z) {
  return __fadd_rn(__fadd_rn(__fmul_rn(x,x), __fmul_rn(y,y)), __fmul_rn(z,z));
}

// ---- wave64 reductions via DPP (LLVM AtomicOptimizer pattern), VALU-pipe only ----
__device__ __forceinline__ int wave_imax(int x) {
  x = max(x, __builtin_amdgcn_update_dpp(0, x, 0x111, 0xf, 0xf, false)); // row_shr:1
  x = max(x, __builtin_amdgcn_update_dpp(0, x, 0x112, 0xf, 0xf, false)); // row_shr:2
  x = max(x, __builtin_amdgcn_update_dpp(0, x, 0x114, 0xf, 0xf, false)); // row_shr:4
  x = max(x, __builtin_amdgcn_update_dpp(0, x, 0x118, 0xf, 0xf, false)); // row_shr:8
  x = max(x, __builtin_amdgcn_update_dpp(0, x, 0x142, 0xa, 0xf, false)); // row_bcast:15
  x = max(x, __builtin_amdgcn_update_dpp(0, x, 0x143, 0xc, 0xf, false)); // row_bcast:31
  return __builtin_amdgcn_readlane(x, 63);
}
__device__ __forceinline__ unsigned wave_umin(unsigned x) {
  x = min(x, (unsigned)__builtin_amdgcn_update_dpp(-1, (int)x, 0x111, 0xf, 0xf, false));
  x = min(x, (unsigned)__builtin_amdgcn_update_dpp(-1, (int)x, 0x112, 0xf, 0xf, false));
  x = min(x, (unsigned)__builtin_amdgcn_update_dpp(-1, (int)x, 0x114, 0xf, 0xf, false));
  x = min(x, (unsigned)__builtin_amdgcn_update_dpp(-1, (int)x, 0x118, 0xf, 0xf, false));
  x = min(x, (unsigned)__builtin_amdgcn_update_dpp(-1, (int)x, 0x142, 0xa, 0xf, false));
  x = min(x, (unsigned)__builtin_amdgcn_update_dpp(-1, (int)x, 0x143, 0xc, 0xf, false));
  return (unsigned)__builtin_amdgcn_readlane((int)x, 63);
}

// ---------------- build (x,y,z,|p|^2) AOS ----------------
__global__ __launch_bounds__(256) void k_xyzw(const float* __restrict__ xyz,
                                              float4* __restrict__ xyzw) {
  int g = blockIdx.x*256 + threadIdx.x;     // < BB*NN
  int b = g >> 13, n = g & (NN-1);
  const float* p = xyz + (size_t)b*3*NN;
  float x = p[n], y = p[NN+n], z = p[2*NN+n];
  xyzw[g] = make_float4(x, y, z, sq3(x,y,z));
}

// ---------------- FPS v5: DPP wave-reduce + LDS point tile ----------------
__global__ __launch_bounds__(256,1) void k_fps(const float4* __restrict__ xyzw,
                                               float4* __restrict__ qw,
                                               int* __restrict__ fpsidx,
                                               float* __restrict__ newxyz) {
  __shared__ float4 tile[NN];       // 128 KiB: all points, centroid broadcast source
  __shared__ u64 skey[2][4];
  int b = blockIdx.x, tid = threadIdx.x;
  const float4* base = xyzw + (size_t)b*NN;
  f32x2 px[16], py[16], pz[16], d2[16];
  #pragma unroll
  for (int j=0;j<16;++j) {
    float4 a = base[j*512 + 2*tid];
    float4 c = base[j*512 + 2*tid + 1];
    tile[j*512 + 2*tid] = a;
    tile[j*512 + 2*tid + 1] = c;
    px[j] = f32x2{a.x, c.x};
    py[j] = f32x2{a.y, c.y};
    pz[j] = f32x2{a.z, c.z};
    d2[j] = f32x2{1e10f, 1e10f};
  }
  float* outx = newxyz + (size_t)b*3*NP;
  float4 p0 = base[0];
  float cx=p0.x, cy=p0.y, cz=p0.z;
  if (tid==0) {
    fpsidx[b*NP] = 0;
    qw[b*NP] = make_float4(p0.x,p0.y,p0.z,sq3(p0.x,p0.y,p0.z));
    outx[0]=p0.x; outx[NP]=p0.y; outx[2*NP]=p0.z;
  }
  int w = tid>>6;
  __syncthreads();
  for (int t=1;t<NP;++t) {
    f32x2 cx2 = {cx,cx}, cy2 = {cy,cy}, cz2 = {cz,cz};
    #pragma unroll
    for (int j=0;j<16;++j) {
      f32x2 dx = px[j]-cx2, dy = py[j]-cy2, dz = pz[j]-cz2;
      f32x2 dd = (dx*dx + dy*dy) + dz*dz;     // contract(off): pk_mul/pk_add, per-op rounding
      d2[j].x = fminf(d2[j].x, dd.x);
      d2[j].y = fminf(d2[j].y, dd.y);
    }
    // argmax tree over 32 leaves; ties -> smaller k (strict-greater keeps left)
    float tv[16]; int tk[16];
    #pragma unroll
    for (int j=0;j<16;++j) {
      bool r = d2[j].y > d2[j].x;
      tv[j] = r ? d2[j].y : d2[j].x;
      tk[j] = r ? 2*j+1 : 2*j;
    }
    #pragma unroll
    for (int j=0;j<8;++j) { bool r = tv[j+8] > tv[j]; if (r){tv[j]=tv[j+8]; tk[j]=tk[j+8];} }
    #pragma unroll
    for (int j=0;j<4;++j) { bool r = tv[j+4] > tv[j]; if (r){tv[j]=tv[j+4]; tk[j]=tk[j+4];} }
    #pragma unroll
    for (int j=0;j<2;++j) { bool r = tv[j+2] > tv[j]; if (r){tv[j]=tv[j+2]; tk[j]=tk[j+2];} }
    bool rr = tv[1] > tv[0];
    float lmax = rr ? tv[1] : tv[0];
    int   k    = rr ? tk[1] : tk[0];
    unsigned gidx = (unsigned)((k>>1)*512 + 2*tid + (k&1));
    // wave winner via two DPP passes (dist bits are non-negative -> int order == float order)
    int mb = wave_imax(__float_as_int(lmax));
    unsigned cand = (__float_as_int(lmax) == mb) ? gidx : 0xFFFFFFFFu;
    unsigned wwin = wave_umin(cand);
    int buf = t & 1;
    if ((tid & 63) == 0)
      skey[buf][w] = ((u64)(unsigned)mb << 32) | (u64)(0xFFFFFFFFu - wwin);
    __syncthreads();
    u64 mk = skey[buf][0];
    if (skey[buf][1] > mk) mk = skey[buf][1];
    if (skey[buf][2] > mk) mk = skey[buf][2];
    if (skey[buf][3] > mk) mk = skey[buf][3];
    unsigned widx = 0xFFFFFFFFu - (unsigned)(mk & 0xFFFFFFFFull);
    float4 cen = tile[widx];            // LDS broadcast (~120 cyc, no VMEM)
    cx = cen.x; cy = cen.y; cz = cen.z;
    if (tid==0) {
      fpsidx[b*NP+t] = (int)widx;
      qw[b*NP+t] = make_float4(cx,cy,cz,sq3(cx,cy,cz));
      outx[t]=cx; outx[NP+t]=cy; outx[2*NP+t]=cz;
    }
  }
}

// ---------------- pre1: W1[:,3:67] @ points + b1, per original point ----------------
__global__ __launch_bounds__(256) void k_pre1(const float* __restrict__ pts,
                                              const float* __restrict__ W1,
                                              const float* __restrict__ b1,
                                              float* __restrict__ pre) {
  int g = blockIdx.x*256 + threadIdx.x;   // b*NN+n
  int b = g >> 13, n = g & (NN-1);
  const float* P = pts + (size_t)b*FIN*NN + n;
  float p[64];
  #pragma unroll
  for (int i=0;i<64;++i) p[i] = P[(size_t)i*NN];
  float4* out = (float4*)(pre + (size_t)g*64);
  for (int og=0; og<16; ++og) {
    float acc[4];
    #pragma unroll
    for (int oo=0;oo<4;++oo) {
      int o = og*4+oo;
      float s = b1[o];
      #pragma unroll
      for (int i=0;i<64;++i) s = fmaf(W1[o*67+3+i], p[i], s);
      acc[oo] = s;
    }
    out[og] = make_float4(acc[0],acc[1],acc[2],acc[3]);
  }
}

// ---------------- KNN v2: one wave per query, lane-distributed sorted top-16 ----------------
__global__ __launch_bounds__(256) void k_knn(const float4* __restrict__ xyzw,
                                             const float4* __restrict__ qw,
                                             int* __restrict__ knnid) {
  int wave = threadIdx.x >> 6, lane = threadIdx.x & 63;
  int q = blockIdx.x*4 + wave;            // 0..16383
  int b = q >> 11;
  float4 Q = qw[q];
  const float4* base = xyzw + (size_t)b*NN;
  float ld = 3.0e38f; int li = 0x7fffffff;   // list entry (lanes 0..15), ascending (d,idx)
  float taud = 3.0e38f; int taui = 0x7fffffff;
  for (int c = 0; c < 128; ++c) {
    int idx = c*64 + lane;
    float4 P = base[idx];
    float dot = __fadd_rn(__fadd_rn(__fmul_rn(P.x,Q.x), __fmul_rn(P.y,Q.y)), __fmul_rn(P.z,Q.z));
    float dd  = __fsub_rn(__fadd_rn(Q.w, P.w), __fmul_rn(2.0f, dot));
    bool better = (dd < taud) || (dd == taud && idx < taui);
    u64 mask = __ballot(better);
    while (mask) {
      int src = __ffsll(mask) - 1;
      mask &= mask - 1;
      float bd = __shfl(dd, src, 64);
      int   bi = __shfl(idx, src, 64);
      bool before = (ld < bd) || (ld == bd && li < bi);
      float sd = __shfl_up(ld, 1, 64);
      int   si = __shfl_up(li, 1, 64);
      int   bp = __shfl_up((int)before, 1, 64);
      bool take_new = !before && (lane == 0 || bp);
      float nd = before ? ld : (take_new ? bd : sd);
      int   ni = before ? li : (take_new ? bi : si);
      if (lane < 16) { ld = nd; li = ni; }
      taud = __shfl(ld, 15, 64);
      taui = __shfl(li, 15, 64);
    }
  }
  if (lane < 16) knnid[q*16 + lane] = li;
}

// ---------------- y1 = W1[:,0:3]@(gxyz - qxyz) + pre1[n] ----------------
__global__ __launch_bounds__(256) void k_y1(const float4* __restrict__ xyzw,
                                            const float4* __restrict__ qw,
                                            const int* __restrict__ knn,
                                            const float* __restrict__ pre,
                                            const float* __restrict__ W1,
                                            float* __restrict__ y) {
  int pos = blockIdx.x*256 + threadIdx.x;   // < NPOS
  int bq = pos >> 4;
  int b  = pos >> 15;
  int n  = knn[pos];
  float4 Q = qw[bq];
  float4 P = xyzw[(b<<13) + n];
  float dx = __fsub_rn(P.x,Q.x), dy = __fsub_rn(P.y,Q.y), dz = __fsub_rn(P.z,Q.z);
  const float4* pr = (const float4*)(pre + ((size_t)(b<<13)+n)*64);
  float4* out = (float4*)(y + (size_t)pos*64);
  for (int og=0; og<16; ++og) {
    float4 acc = pr[og];
    float a[4] = {acc.x, acc.y, acc.z, acc.w};
    #pragma unroll
    for (int oo=0;oo<4;++oo) {
      int o = og*4+oo;
      a[oo] = fmaf(W1[o*67+0], dx, fmaf(W1[o*67+1], dy, fmaf(W1[o*67+2], dz, a[oo])));
    }
    out[og] = make_float4(a[0],a[1],a[2],a[3]);
  }
}

// ---------------- per-channel sum / sumsq (layer1) ----------------
__global__ __launch_bounds__(256) void k_stats(const float* __restrict__ y,
                                               float* __restrict__ st) {
  __shared__ float s1[256], s2[256];
  int tid = threadIdx.x; int c = tid & 63, r = tid >> 6;
  size_t base = (size_t)blockIdx.x * 1024;
  float sum = 0.f, ss = 0.f;
  for (int i=0;i<256;++i) {
    float v = y[(base + (size_t)i*4 + r)*64 + c];
    sum += v; ss = fmaf(v, v, ss);
  }
  s1[tid]=sum; s2[tid]=ss;
  __syncthreads();
  if (tid < 64) {
    float t1 = s1[tid]+s1[tid+64]+s1[tid+128]+s1[tid+192];
    float t2 = s2[tid]+s2[tid+64]+s2[tid+128]+s2[tid+192];
    atomicAdd(&st[tid], t1);
    atomicAdd(&st[64+tid], t2);
  }
}

__global__ void k_bnp(const float* __restrict__ st, const float* __restrict__ g,
                      const float* __restrict__ be, float* __restrict__ bnp) {
  int c = threadIdx.x;     // 64
  float mean = st[c] * (1.0f/NPOS);
  float var  = st[64+c] * (1.0f/NPOS) - mean*mean;
  float istd = 1.0f / sqrtf(var + 1e-5f);
  float s = g[c]*istd;
  bnp[c] = s;
  bnp[64+c] = be[c] - mean*s;
}

// ---------------- act: in-place x = relu(s*x + t) ----------------
__global__ __launch_bounds__(256) void k_act(float* __restrict__ y,
                                             const float* __restrict__ bnp) {
  size_t g = (size_t)blockIdx.x*256 + threadIdx.x;
  float4* Y = (float4*)y;
  #pragma unroll
  for (int r=0;r<4;++r) {
    size_t f4 = g + (size_t)r*1048576;               // 4,194,304 float4 total
    int c0 = (int)((f4*4) & 63);
    float4 s4 = *(const float4*)(bnp + c0);
    float4 t4 = *(const float4*)(bnp + 64 + c0);
    float4 v = Y[f4];
    v.x = fmaxf(0.f, fmaf(v.x, s4.x, t4.x));
    v.y = fmaxf(0.f, fmaf(v.y, s4.y, t4.y));
    v.z = fmaxf(0.f, fmaf(v.z, s4.z, t4.z));
    v.w = fmaxf(0.f, fmaf(v.w, s4.w, t4.w));
    Y[f4] = v;
  }
}

// ---------------- dot of 64 with 4 partial accumulators ----------------
__device__ __forceinline__ float dot64(const float4* x, const float* W, float init) {
  float a0 = init, a1 = 0.f, a2 = 0.f, a3 = 0.f;
  #pragma unroll
  for (int j=0;j<16;++j) {
    float4 v = x[j];
    a0 = fmaf(v.x, W[4*j],   a0);
    a1 = fmaf(v.y, W[4*j+1], a1);
    a2 = fmaf(v.z, W[4*j+2], a2);
    a3 = fmaf(v.w, W[4*j+3], a3);
  }
  return (a0+a1)+(a2+a3);
}

// ---------------- conv2: W in VGPRs (lane=out ch), in-place, fused stats2 ----------------
__global__ __launch_bounds__(256) void k_conv2v(float* __restrict__ y,
                                                const float* __restrict__ W2,
                                                const float* __restrict__ b2,
                                                float* __restrict__ st2) {
  __shared__ float r1[4][64], r2[4][64];
  int wave = threadIdx.x>>6;
  int wid = blockIdx.x*4 + wave;   // 0..2047
  int lane = threadIdx.x & 63;
  float W[64];
  #pragma unroll
  for (int j=0;j<16;++j) {
    float4 t = *(const float4*)(W2 + (size_t)lane*64 + j*4);
    W[4*j]=t.x; W[4*j+1]=t.y; W[4*j+2]=t.z; W[4*j+3]=t.w;
  }
  float bb = b2[lane];
  size_t p0 = (size_t)wid*128;
  const float4* src = (const float4*)(y + p0*64);
  float4 xa[16], xb[16];
  float sum = 0.f, ss = 0.f;
  #pragma unroll
  for (int j=0;j<16;++j) xa[j] = src[j];
  for (int p=0;p<128;p+=2) {
    #pragma unroll
    for (int j=0;j<16;++j) xb[j] = src[(p+1)*16 + j];
    float acc = dot64(xa, W, bb);
    y[(p0+p)*64 + lane] = acc;
    sum += acc; ss = fmaf(acc, acc, ss);
    if (p+2 < 128) {
      #pragma unroll
      for (int j=0;j<16;++j) xa[j] = src[(p+2)*16 + j];
    }
    float acc2 = dot64(xb, W, bb);
    y[(p0+p+1)*64 + lane] = acc2;
    sum += acc2; ss = fmaf(acc2, acc2, ss);
  }
  r1[wave][lane] = sum; r2[wave][lane] = ss;
  __syncthreads();
  if (threadIdx.x < 64) {
    int l = threadIdx.x;
    float t1 = r1[0][l]+r1[1][l]+r1[2][l]+r1[3][l];
    float t2 = r2[0][l]+r2[1][l]+r2[2][l]+r2[3][l];
    atomicAdd(&st2[l], t1);
    atomicAdd(&st2[64+l], t2);
  }
}

// ---------------- conv3 + max over K: W in VGPRs, half-split ----------------
__global__ __launch_bounds__(256) void k_c3v(const float* __restrict__ y,
                                             const float* __restrict__ W3,
                                             const float* __restrict__ b3,
                                             float* __restrict__ feat) {
  int wid = blockIdx.x*4 + (threadIdx.x>>6);   // 0..2047
  int lane = threadIdx.x & 63;
  int h = wid & 1, chunk = wid >> 1;           // 1024 chunks x 16 queries
  float W[64];
  #pragma unroll
  for (int j=0;j<16;++j) {
    float4 t = *(const float4*)(W3 + ((size_t)(h*64+lane))*64 + j*4);
    W[4*j]=t.x; W[4*j+1]=t.y; W[4*j+2]=t.z; W[4*j+3]=t.w;
  }
  float bb = b3[h*64+lane];
  const float4* src = (const float4*)(y + (size_t)chunk*16*16*64);
  float4 xa[16], xb[16];
  #pragma unroll
  for (int j=0;j<16;++j) xa[j] = src[j];
  int pos = 0;
  for (int q=0;q<16;++q) {
    float m = -3.0e38f;
    #pragma unroll 1
    for (int k=0;k<16;k+=2) {
      #pragma unroll
      for (int j=0;j<16;++j) xb[j] = src[(pos+1)*16 + j];
      m = fmaxf(m, dot64(xa, W, bb));
      if (pos+2 < 256) {
        #pragma unroll
        for (int j=0;j<16;++j) xa[j] = src[(pos+2)*16 + j];
      }
      m = fmaxf(m, dot64(xb, W, bb));
      pos += 2;
    }
    int gq = chunk*16 + q;
    int b = gq >> 11, qq = gq & (NP-1);
    feat[((size_t)(b*128 + h*64 + lane))*NP + qq] = m;
  }
}

extern "C" void kernel_launch(void* const* d_in, const int* in_sizes, int n_in,
                              void* d_out, int out_size, void* d_ws, size_t ws_size,
                              hipStream_t stream) {
  const float* xyz = (const float*)d_in[0];
  const float* pts = (const float*)d_in[1];
  const float* W1  = (const float*)d_in[2];
  const float* b1  = (const float*)d_in[3];
  const float* g1  = (const float*)d_in[4];
  const float* be1 = (const float*)d_in[5];
  const float* W2  = (const float*)d_in[6];
  const float* b2  = (const float*)d_in[7];
  const float* g2  = (const float*)d_in[8];
  const float* be2 = (const float*)d_in[9];
  const float* W3  = (const float*)d_in[10];
  const float* b3  = (const float*)d_in[11];
  float* out = (float*)d_out;
  float* ws  = (float*)d_ws;

  // workspace layout (float offsets)
  float4* xyzw  = (float4*)ws;                    //  65536 float4
  float4* qw    = (float4*)(ws + 262144);         //  16384 float4
  int*    fpsid = (int*)(ws + 327680);            //  16384
  int*    knnid = (int*)(ws + 344064);            //  262144
  float*  pre   = ws + 1654784;                   //  4194304
  float*  ybuf  = ws + 5849088;                   //  16777216
  float*  stats = ws + 22626304;                  //  256
  float*  bnp   = ws + 22626560;                  //  256

  hipMemsetAsync(stats, 0, 256*sizeof(float), stream);

  k_xyzw  <<<256, 256, 0, stream>>>(xyz, xyzw);
  k_pre1  <<<256, 256, 0, stream>>>(pts, W1, b1, pre);
  k_fps   <<<8, 256, 0, stream>>>(xyzw, qw, fpsid, out);
  k_knn   <<<4096, 256, 0, stream>>>(xyzw, qw, knnid);
  k_y1    <<<1024, 256, 0, stream>>>(xyzw, qw, knnid, pre, W1, ybuf);
  k_stats <<<256, 256, 0, stream>>>(ybuf, stats);
  k_bnp   <<<1, 64, 0, stream>>>(stats, g1, be1, bnp);
  k_act   <<<4096, 256, 0, stream>>>(ybuf, bnp);
  k_conv2v<<<512, 256, 0, stream>>>(ybuf, W2, b2, stats + 128);
  k_bnp   <<<1, 64, 0, stream>>>(stats + 128, g2, be2, bnp + 128);
  k_act   <<<4096, 256, 0, stream>>>(ybuf, bnp + 128);
  k_c3v   <<<512, 256, 0, stream>>>(ybuf, W3, b3, out + 49152);
}